// Round 5
// baseline (5098.930 us; speedup 1.0000x reference)
//
#include <hip/hip_runtime.h>

constexpr int T  = 1024;
constexpr int B  = 32;
constexpr int I  = 64;
constexpr int H  = 1024;
constexpr int OF = 64;
constexpr int OC = 8;
constexpr int K  = H + I;     // 1088 = h2h ++ i2h folded
constexpr int NGROUPS = 16;   // sync groups (2 batches each)
constexpr int NMEMB   = 16;   // workgroups per group
constexpr int BPG = 2;        // batches per group
constexpr int CH  = 136;      // per-lane contiguous k-chunk (K/8)
constexpr int CHP = 140;      // padded chunk stride (12*l8 mod 32 spreads banks)
constexpr int BSTR = 8 * CHP; // 1120 words per batch in LDS
constexpr long long OUT1_OFF = (long long)T * B * OF;
constexpr long long OUT2_OFF = (long long)T * B * (OF + OC);

// Agent-scope relaxed ops: global_{load,store} sc0 sc1 — bypass L1/L2, meet at
// the L3 coherence point. Fence-free. R2/R3-proven for producer/consumer.
__device__ __forceinline__ void st_agent_f32(float* p, float v) {
  __hip_atomic_store(p, v, __ATOMIC_RELAXED, __HIP_MEMORY_SCOPE_AGENT);
}
__device__ __forceinline__ void st_agent_u32(unsigned* p, unsigned v) {
  __hip_atomic_store(p, v, __ATOMIC_RELAXED, __HIP_MEMORY_SCOPE_AGENT);
}
__device__ __forceinline__ unsigned ld_agent_u32(const unsigned* p) {
  return __hip_atomic_load(p, __ATOMIC_RELAXED, __HIP_MEMORY_SCOPE_AGENT);
}
__device__ __forceinline__ unsigned long long ld_agent_u64(const float* p) {
  return __hip_atomic_load((const unsigned long long*)p, __ATOMIC_RELAXED,
                           __HIP_MEMORY_SCOPE_AGENT);
}
__device__ __forceinline__ bool has_sent(unsigned long long v) {
  return ((unsigned)v == 0xFFFFFFFFu) || ((unsigned)(v >> 32) == 0xFFFFFFFFu);
}
// Fast-path pair load: sc0-only (L1-bypass, L2-lookup). Loads + waitcnt live in
// ONE asm block; consumers depend on asm OUTPUTS, so no hoisting hazard.
// Used ONLY as a bounded-retry accelerator; correctness never depends on it.
__device__ __forceinline__ void ld_xcd_pair(const float* p0, const float* p1,
                                            unsigned long long& v0,
                                            unsigned long long& v1) {
  asm volatile("global_load_dwordx2 %0, %2, off sc0\n\t"
               "global_load_dwordx2 %1, %3, off sc0\n\t"
               "s_waitcnt vmcnt(0)"
               : "=&v"(v0), "=&v"(v1)
               : "v"(p0), "v"(p1)
               : "memory");
}

// ---------------------------------------------------------------------------
// Recurrence: 256 persistent WGs x 512 threads (1/CU), group g = bid&15 owns
// batches {2g, 2g+1}; member m = bid>>4 owns rows [m*64, m*64+64).
// Thread (jrel = tid>>3, l8 = tid&7): row j0+jrel, k-chunk [l8*136, +136).
// Weights register-stationary (136 fp32/thread in ArchVGPRs; launch_bounds(512)
// -> 256-VGPR budget). Exchange: sentinel-polled coherent loads on rate_all
// (NaN 0xFFFFFFFF fill). Stores are ALWAYS agent-scope (L3-visible, proven).
// If tid0 verifies all 16 members share an XCD (HW_REG_XCC_ID), loads first
// try sc0-only (XCD L2) with a BOUNDED retry, then fall back to agent loads.
// Every wait loop is bounded or R2-proven => no hang possible.
// ---------------------------------------------------------------------------
__global__ __launch_bounds__(512) void rnn_recur(
    const float* __restrict__ input_sig, const float* __restrict__ rate0,
    const float* __restrict__ i2h_w, const float* __restrict__ i2h_b,
    const float* __restrict__ h2h_w, const float* __restrict__ h2h_b,
    float* __restrict__ rate_all, unsigned* __restrict__ ids)
{
  const int tid = threadIdx.x;
  const int bid = blockIdx.x;
  const int g   = bid & (NGROUPS - 1);
  const int m   = bid >> 4;
  const int j0  = m * 64;
  const int l8  = tid & 7;
  const int jrel = tid >> 3;
  const int j   = j0 + jrel;
  const int bG  = g * BPG;

  __shared__ float r_lds[2][BPG * BSTR];  // double-buffered state
  __shared__ int fast_flag;

  // ---- one-time XCD co-residency check (tid0 only, bounded polls)
  if (tid == 0) {
    unsigned xcc;
    asm volatile("s_getreg_b32 %0, hwreg(HW_REG_XCC_ID)" : "=s"(xcc));
    st_agent_u32(&ids[bid], xcc + 1u);   // 1..8, never the 0xFF sentinel
    bool same = true;
    for (int mm = 0; mm < NMEMB; ++mm) {
      unsigned v = 0xFFFFFFFFu;
      for (int it = 0; it < (1 << 16) && v == 0xFFFFFFFFu; ++it)
        v = ld_agent_u32(&ids[mm * NMEMB + g]);
      same &= (v == xcc + 1u);           // timeout leaves sentinel -> false
    }
    fast_flag = same ? 1 : 0;
  }

  // ---- register-stationary weights: 34 float4 = 136 fp32 per thread
  float4 w4[34];
#pragma unroll
  for (int q = 0; q < 34; ++q) {
    const int k = l8 * CH + q * 4;
    w4[q] = (k < H) ? *(const float4*)(h2h_w + (long long)j * H + k)
                    : *(const float4*)(i2h_w + (long long)j * I + (k - H));
  }
  const float bsum = h2h_b[j] + i2h_b[j];
  const int posj = (j / CH) * CHP + (j % CH);

  // ---- initial stage into buf0: rate0 + input_sig[0] (plain cached loads)
  {
    const int b = tid >> 8, u4 = tid & 255;
    const int k0 = u4 * 4, c = k0 / CH, off = k0 - c * CH;
    float4 v = *(const float4*)(rate0 + (long long)(bG + b) * H + k0);
    *(float4*)&r_lds[0][b * BSTR + c * CHP + off] = v;
    if (tid < 32) {
      const int b2 = tid >> 4, iq = tid & 15;
      float4 u = *(const float4*)(input_sig + (long long)(bG + b2) * I + iq * 4);
      *(float4*)&r_lds[0][b2 * BSTR + 7 * CHP + 72 + iq * 4] = u;
    }
  }
  __syncthreads();
  const bool fast = (fast_flag != 0);

  for (int t = 0; t < T; ++t) {
    const int cur = t & 1, nxt = cur ^ 1;
    const float* Rb = &r_lds[cur][0];

    // prefetch x_{t+1} into regs (32 threads); LDS write deferred past poll
    float4 xnext;
    const bool xstage = (tid < 32) && (t + 1 < T);
    if (xstage) {
      xnext = *(const float4*)(input_sig +
          ((long long)(t + 1) * B + bG + (tid >> 4)) * I + (tid & 15) * 4);
    }

    float a0 = 0.f, a1 = 0.f;
#pragma unroll
    for (int q = 0; q < 34; ++q) {
      const float4 r0 = *(const float4*)&Rb[l8 * CHP + q * 4];
      const float4 r1 = *(const float4*)&Rb[BSTR + l8 * CHP + q * 4];
      a0 = fmaf(w4[q].x, r0.x, a0); a1 = fmaf(w4[q].x, r1.x, a1);
      a0 = fmaf(w4[q].y, r0.y, a0); a1 = fmaf(w4[q].y, r1.y, a1);
      a0 = fmaf(w4[q].z, r0.z, a0); a1 = fmaf(w4[q].z, r1.z, a1);
      a0 = fmaf(w4[q].w, r0.w, a0); a1 = fmaf(w4[q].w, r1.w, a1);
    }
#pragma unroll
    for (int off = 4; off >= 1; off >>= 1) {
      a0 += __shfl_xor(a0, off, 64);
      a1 += __shfl_xor(a1, off, 64);
    }
    // lanes l8=0/1 own batch 0/1 of row j; store agent-scope (ALWAYS)
    if (l8 < 2) {
      const float pre  = ((l8 == 0) ? a0 : a1) + bsum;
      const float rold = r_lds[cur][l8 * BSTR + posj];
      const float rnew = 0.9f * rold + 0.1f * tanhf(pre);
      st_agent_f32(&rate_all[((long long)t * B + (bG + l8)) * H + j], rnew);
    }

    if (t + 1 < T) {
      const float* srcR = rate_all + ((long long)t * B + bG) * H;
      const float* p0 = srcR + 2 * tid;       // batch 0, k = 2*tid
      const float* p1 = srcR + H + 2 * tid;   // batch 1
      unsigned long long v0 = 0xFFFFFFFFFFFFFFFFull, v1 = v0;
      if (fast) {
        // bounded sc0-only attempts through the shared XCD L2
        int tries = 16;
        do { ld_xcd_pair(p0, p1, v0, v1); }
        while ((has_sent(v0) || has_sent(v1)) && --tries);
      } else {
        v0 = ld_agent_u64(p0); v1 = ld_agent_u64(p1);
      }
      // proven agent-scope finisher (no-op when data already in hand);
      // reload BOTH per round -> one L3 latency covers both batches
      while (has_sent(v0) || has_sent(v1)) {
        v0 = ld_agent_u64(p0); v1 = ld_agent_u64(p1);
      }
      const int c = tid / 68, off = 2 * tid - c * CH;
      *(unsigned long long*)&r_lds[nxt][c * CHP + off] = v0;
      *(unsigned long long*)&r_lds[nxt][BSTR + c * CHP + off] = v1;
      if (xstage) {
        *(float4*)&r_lds[nxt][(tid >> 4) * BSTR + 7 * CHP + 72 + (tid & 15) * 4] = xnext;
      }
    }
    __syncthreads();
  }
}

// ---------------------------------------------------------------------------
// Readout: C[32768,72] = rate_all[32768,1024] x [h2o_w;h2o_ctx_w]^T + bias
// ---------------------------------------------------------------------------
__global__ __launch_bounds__(256) void rnn_readout(
    const float* __restrict__ rate_all,
    const float* __restrict__ h2o_w, const float* __restrict__ h2o_b,
    const float* __restrict__ h2o_ctx_w, const float* __restrict__ h2o_ctx_b,
    float* __restrict__ out0, float* __restrict__ out1)
{
  constexpr int RB = 128;
  constexpr int HC = 128;
  constexpr int SR = HC + 1;
  __shared__ float rl[RB * SR];
  __shared__ float wl[72 * SR];

  const int tid = threadIdx.x;
  const long long row0 = (long long)blockIdx.x * RB;
  const int rb = tid & 31, og = tid >> 5;

  float acc[4][9];
#pragma unroll
  for (int c = 0; c < 4; ++c)
#pragma unroll
    for (int i = 0; i < 9; ++i) acc[c][i] = 0.f;

  for (int hc = 0; hc < H / HC; ++hc) {
#pragma unroll
    for (int i = 0; i < 16; ++i) {
      const int q = i * 256 + tid;
      const int row = q >> 5, hq = q & 31;
      float4 v = *(const float4*)(rate_all + (row0 + row) * H + hc * HC + hq * 4);
      float* d = &rl[row * SR + hq * 4];
      d[0] = v.x; d[1] = v.y; d[2] = v.z; d[3] = v.w;
    }
#pragma unroll
    for (int i = 0; i < 9; ++i) {
      const int q = i * 256 + tid;
      const int o = q >> 5, hq = q & 31;
      const float* src = (o < OF) ? (h2o_w + (long long)o * H)
                                  : (h2o_ctx_w + (long long)(o - OF) * H);
      float4 v = *(const float4*)(src + hc * HC + hq * 4);
      float* d = &wl[o * SR + hq * 4];
      d[0] = v.x; d[1] = v.y; d[2] = v.z; d[3] = v.w;
    }
    __syncthreads();

#pragma unroll 4
    for (int h = 0; h < HC; ++h) {
      const float r0 = rl[(rb)      * SR + h];
      const float r1 = rl[(rb + 32) * SR + h];
      const float r2 = rl[(rb + 64) * SR + h];
      const float r3 = rl[(rb + 96) * SR + h];
#pragma unroll
      for (int i = 0; i < 9; ++i) {
        const float wv = wl[(og * 9 + i) * SR + h];
        acc[0][i] = fmaf(r0, wv, acc[0][i]);
        acc[1][i] = fmaf(r1, wv, acc[1][i]);
        acc[2][i] = fmaf(r2, wv, acc[2][i]);
        acc[3][i] = fmaf(r3, wv, acc[3][i]);
      }
    }
    __syncthreads();
  }

#pragma unroll
  for (int c = 0; c < 4; ++c) {
    const long long row = row0 + rb + 32 * c;
#pragma unroll
    for (int i = 0; i < 9; ++i) {
      const int o = og * 9 + i;
      if (o < OF) out0[row * OF + o] = acc[c][i] + h2o_b[o];
      else        out1[row * OC + (o - OF)] = acc[c][i] + h2o_ctx_b[o - OF];
    }
  }
}

extern "C" void kernel_launch(void* const* d_in, const int* in_sizes, int n_in,
                              void* d_out, int out_size, void* d_ws, size_t ws_size,
                              hipStream_t stream) {
  (void)in_sizes; (void)n_in; (void)d_ws; (void)ws_size; (void)out_size;
  const float* input_sig = (const float*)d_in[0];
  const float* rate0     = (const float*)d_in[1];
  const float* i2h_w     = (const float*)d_in[2];
  const float* i2h_b     = (const float*)d_in[3];
  const float* h2h_w     = (const float*)d_in[4];
  const float* h2h_b     = (const float*)d_in[5];
  const float* h2o_w     = (const float*)d_in[6];
  const float* h2o_b     = (const float*)d_in[7];
  const float* h2o_ctx_w = (const float*)d_in[8];
  const float* h2o_ctx_b = (const float*)d_in[9];

  float* out      = (float*)d_out;
  float* out0     = out;
  float* out1     = out + OUT1_OFF;
  float* rate_all = out + OUT2_OFF;
  // XCC-ID slots live in the first 1KB of out0 during the recurrence; the
  // readout kernel overwrites that region with real outputs afterwards.
  unsigned* ids = (unsigned*)d_out;

  // Sentinel fills: finite arithmetic can never produce 0xFFFFFFFF (NaN).
  hipMemsetAsync(ids, 0xFF, 256 * sizeof(unsigned), stream);
  hipMemsetAsync(rate_all, 0xFF, (size_t)T * B * H * sizeof(float), stream);
  hipLaunchKernelGGL(rnn_recur, dim3(NGROUPS * NMEMB), dim3(512), 0, stream,
                     input_sig, rate0, i2h_w, i2h_b, h2h_w, h2h_b, rate_all, ids);
  hipLaunchKernelGGL(rnn_readout, dim3(256), dim3(256), 0, stream,
                     rate_all, h2o_w, h2o_b, h2o_ctx_w, h2o_ctx_b, out0, out1);
}

// Round 6
// 4982.515 us; speedup vs baseline: 1.0234x; 1.0234x over previous
//
#include <hip/hip_runtime.h>

constexpr int T  = 1024;
constexpr int B  = 32;
constexpr int I  = 64;
constexpr int H  = 1024;
constexpr int OF = 64;
constexpr int OC = 8;
constexpr int K  = H + I;     // 1088 = h2h ++ i2h folded
constexpr int NGROUPS = 16;   // groups (2 batches each)
constexpr int NMEMB   = 16;   // workgroups per group
constexpr int BPG = 2;        // batches per group
constexpr int CH  = 136;      // per-lane contiguous k-chunk (K/8)
constexpr int CHP = 140;      // padded chunk stride (12*l8 mod 32 spreads banks)
constexpr int BSTR = 8 * CHP; // 1120 words per batch in LDS
constexpr long long OUT1_OFF = (long long)T * B * OF;
constexpr long long OUT2_OFF = (long long)T * B * (OF + OC);

// Agent-scope relaxed ops: global_{load,store} sc0 sc1 — bypass L1/L2, meet at
// the L3 coherence point. Fence-free. R2/R3/R5-proven for producer/consumer.
// NOTE (R4/R5 lesson): sc0-only loads can NEVER observe sc0sc1 stores — the
// consumer's L2 caches a stale line forever. All cross-WG traffic is sc0sc1.
__device__ __forceinline__ void st_agent_u64(unsigned long long* p,
                                             unsigned long long v) {
  __hip_atomic_store(p, v, __ATOMIC_RELAXED, __HIP_MEMORY_SCOPE_AGENT);
}
__device__ __forceinline__ unsigned long long
ld_agent_u64(const unsigned long long* p) {
  return __hip_atomic_load(p, __ATOMIC_RELAXED, __HIP_MEMORY_SCOPE_AGENT);
}

// ---------------------------------------------------------------------------
// Recurrence: 256 persistent WGs x 512 threads (1/CU), group g = bid&15 owns
// batches {2g, 2g+1}; member m = bid>>4 owns rows [m*64, m*64+64).
// Thread (jrel = tid>>3, l8 = tid&7): row j0+jrel, k-chunk [l8*136, +136).
// Weights register-stationary (136 fp32/thread).
//
// Exchange: tagged 2-slot ring (u64 = {f32 val, u32 tag=t+1}) in the first
// 512KB of out0, hot in L3. Step t writes slot t&1 with tag t+1; consumers
// poll their own packets until the tag matches — the data load IS the sync
// (no counters, no flags, no sentinel re-init, no cold-HBM polls).
// 2-slot reuse is safe: a WG writes slot s at step t+2 only after its step
// t+1 poll saw every WG's tag-(t+2) packets, which (program order + the one
// per-step barrier) implies every WG finished reading slot s at step t.
// Ring memset to 0 each call => stale tags can never equal an expected tag.
// rate_all is written with plain cached stores (kernel-end flush makes it
// visible to the readout dispatch).
// ---------------------------------------------------------------------------
__global__ __launch_bounds__(512, 1) void rnn_recur(
    const float* __restrict__ input_sig, const float* __restrict__ rate0,
    const float* __restrict__ i2h_w, const float* __restrict__ i2h_b,
    const float* __restrict__ h2h_w, const float* __restrict__ h2h_b,
    float* __restrict__ rate_all, unsigned long long* __restrict__ ring)
{
  const int tid = threadIdx.x;
  const int bid = blockIdx.x;
  const int g   = bid & (NGROUPS - 1);
  const int m   = bid >> 4;
  const int j0  = m * 64;
  const int l8  = tid & 7;
  const int jrel = tid >> 3;
  const int j   = j0 + jrel;
  const int bG  = g * BPG;

  __shared__ float r_lds[2][BPG * BSTR];  // double-buffered state

  // ---- register-stationary weights: 34 float4 = 136 fp32 per thread
  float4 w4[34];
#pragma unroll
  for (int q = 0; q < 34; ++q) {
    const int k = l8 * CH + q * 4;
    w4[q] = (k < H) ? *(const float4*)(h2h_w + (long long)j * H + k)
                    : *(const float4*)(i2h_w + (long long)j * I + (k - H));
  }
  const float bsum = h2h_b[j] + i2h_b[j];
  const int posj = (j / CH) * CHP + (j % CH);

  // ---- initial stage into buf0: r_{-1}=rate0 + input_sig[0] (plain loads)
  {
    const int b = tid >> 8, u4 = tid & 255;
    const int k0 = u4 * 4, c = k0 / CH, off = k0 - c * CH;
    float4 v = *(const float4*)(rate0 + (long long)(bG + b) * H + k0);
    *(float4*)&r_lds[0][b * BSTR + c * CHP + off] = v;
    if (tid < 32) {
      const int b2 = tid >> 4, iq = tid & 15;
      float4 u = *(const float4*)(input_sig + (long long)(bG + b2) * I + iq * 4);
      *(float4*)&r_lds[0][b2 * BSTR + 7 * CHP + 72 + iq * 4] = u;
    }
  }
  __syncthreads();

  for (int t = 0; t < T; ++t) {
    const int cur = t & 1, nxt = cur ^ 1;
    const float* Rb = &r_lds[cur][0];

    // prefetch x_{t+1} into regs (32 threads); LDS write deferred past poll
    float4 xnext;
    const bool xstage = (tid < 32) && (t + 1 < T);
    if (xstage) {
      xnext = *(const float4*)(input_sig +
          ((long long)(t + 1) * B + bG + (tid >> 4)) * I + (tid & 15) * 4);
    }

    float a0 = 0.f, a1 = 0.f;
#pragma unroll
    for (int q = 0; q < 34; ++q) {
      const float4 r0 = *(const float4*)&Rb[l8 * CHP + q * 4];
      const float4 r1 = *(const float4*)&Rb[BSTR + l8 * CHP + q * 4];
      a0 = fmaf(w4[q].x, r0.x, a0); a1 = fmaf(w4[q].x, r1.x, a1);
      a0 = fmaf(w4[q].y, r0.y, a0); a1 = fmaf(w4[q].y, r1.y, a1);
      a0 = fmaf(w4[q].z, r0.z, a0); a1 = fmaf(w4[q].z, r1.z, a1);
      a0 = fmaf(w4[q].w, r0.w, a0); a1 = fmaf(w4[q].w, r1.w, a1);
    }
#pragma unroll
    for (int off = 4; off >= 1; off >>= 1) {
      a0 += __shfl_xor(a0, off, 64);
      a1 += __shfl_xor(a1, off, 64);
    }
    // lanes l8=0/1 own batch 0/1 of row j: tagged ring packet + plain rate_all
    if (l8 < 2) {
      const float pre  = ((l8 == 0) ? a0 : a1) + bsum;
      const float rold = r_lds[cur][l8 * BSTR + posj];
      const float rnew = 0.9f * rold + 0.1f * tanhf(pre);
      const unsigned long long pkt =
          ((unsigned long long)(unsigned)(t + 1) << 32) |
          (unsigned long long)__float_as_uint(rnew);
      st_agent_u64(&ring[((long long)(t & 1) * B + (bG + l8)) * H + j], pkt);
      rate_all[((long long)t * B + (bG + l8)) * H + j] = rnew;  // plain cached
    }

    if (t + 1 < T) {
      // poll our own 4 packets of r_t (both batches, k=2tid..2tid+1);
      // all four loads in flight per round -> one L3 RT per retry round
      const unsigned long long* s0 =
          &ring[((long long)(t & 1) * B + bG) * H + 2 * tid];
      const unsigned long long* s1 = s0 + H;
      const unsigned tag = (unsigned)(t + 1);
      unsigned long long a0p, a1p, b0p, b1p;
      do {
        a0p = ld_agent_u64(s0);
        a1p = ld_agent_u64(s0 + 1);
        b0p = ld_agent_u64(s1);
        b1p = ld_agent_u64(s1 + 1);
      } while ((unsigned)(a0p >> 32) != tag || (unsigned)(a1p >> 32) != tag ||
               (unsigned)(b0p >> 32) != tag || (unsigned)(b1p >> 32) != tag);
      const int c = tid / 68, off = 2 * tid - c * CH;
      float2 f0, f1;
      f0.x = __uint_as_float((unsigned)a0p);
      f0.y = __uint_as_float((unsigned)a1p);
      f1.x = __uint_as_float((unsigned)b0p);
      f1.y = __uint_as_float((unsigned)b1p);
      *(float2*)&r_lds[nxt][c * CHP + off] = f0;
      *(float2*)&r_lds[nxt][BSTR + c * CHP + off] = f1;
      if (xstage) {
        *(float4*)&r_lds[nxt][(tid >> 4) * BSTR + 7 * CHP + 72 + (tid & 15) * 4] = xnext;
      }
    }
    __syncthreads();
  }
}

// ---------------------------------------------------------------------------
// Readout: C[32768,72] = rate_all[32768,1024] x [h2o_w;h2o_ctx_w]^T + bias
// ---------------------------------------------------------------------------
__global__ __launch_bounds__(256) void rnn_readout(
    const float* __restrict__ rate_all,
    const float* __restrict__ h2o_w, const float* __restrict__ h2o_b,
    const float* __restrict__ h2o_ctx_w, const float* __restrict__ h2o_ctx_b,
    float* __restrict__ out0, float* __restrict__ out1)
{
  constexpr int RB = 128;
  constexpr int HC = 128;
  constexpr int SR = HC + 1;
  __shared__ float rl[RB * SR];
  __shared__ float wl[72 * SR];

  const int tid = threadIdx.x;
  const long long row0 = (long long)blockIdx.x * RB;
  const int rb = tid & 31, og = tid >> 5;

  float acc[4][9];
#pragma unroll
  for (int c = 0; c < 4; ++c)
#pragma unroll
    for (int i = 0; i < 9; ++i) acc[c][i] = 0.f;

  for (int hc = 0; hc < H / HC; ++hc) {
#pragma unroll
    for (int i = 0; i < 16; ++i) {
      const int q = i * 256 + tid;
      const int row = q >> 5, hq = q & 31;
      float4 v = *(const float4*)(rate_all + (row0 + row) * H + hc * HC + hq * 4);
      float* d = &rl[row * SR + hq * 4];
      d[0] = v.x; d[1] = v.y; d[2] = v.z; d[3] = v.w;
    }
#pragma unroll
    for (int i = 0; i < 9; ++i) {
      const int q = i * 256 + tid;
      const int o = q >> 5, hq = q & 31;
      const float* src = (o < OF) ? (h2o_w + (long long)o * H)
                                  : (h2o_ctx_w + (long long)(o - OF) * H);
      float4 v = *(const float4*)(src + hc * HC + hq * 4);
      float* d = &wl[o * SR + hq * 4];
      d[0] = v.x; d[1] = v.y; d[2] = v.z; d[3] = v.w;
    }
    __syncthreads();

#pragma unroll 4
    for (int h = 0; h < HC; ++h) {
      const float r0 = rl[(rb)      * SR + h];
      const float r1 = rl[(rb + 32) * SR + h];
      const float r2 = rl[(rb + 64) * SR + h];
      const float r3 = rl[(rb + 96) * SR + h];
#pragma unroll
      for (int i = 0; i < 9; ++i) {
        const float wv = wl[(og * 9 + i) * SR + h];
        acc[0][i] = fmaf(r0, wv, acc[0][i]);
        acc[1][i] = fmaf(r1, wv, acc[1][i]);
        acc[2][i] = fmaf(r2, wv, acc[2][i]);
        acc[3][i] = fmaf(r3, wv, acc[3][i]);
      }
    }
    __syncthreads();
  }

#pragma unroll
  for (int c = 0; c < 4; ++c) {
    const long long row = row0 + rb + 32 * c;
#pragma unroll
    for (int i = 0; i < 9; ++i) {
      const int o = og * 9 + i;
      if (o < OF) out0[row * OF + o] = acc[c][i] + h2o_b[o];
      else        out1[row * OC + (o - OF)] = acc[c][i] + h2o_ctx_b[o - OF];
    }
  }
}

extern "C" void kernel_launch(void* const* d_in, const int* in_sizes, int n_in,
                              void* d_out, int out_size, void* d_ws, size_t ws_size,
                              hipStream_t stream) {
  (void)in_sizes; (void)n_in; (void)d_ws; (void)ws_size; (void)out_size;
  const float* input_sig = (const float*)d_in[0];
  const float* rate0     = (const float*)d_in[1];
  const float* i2h_w     = (const float*)d_in[2];
  const float* i2h_b     = (const float*)d_in[3];
  const float* h2h_w     = (const float*)d_in[4];
  const float* h2h_b     = (const float*)d_in[5];
  const float* h2o_w     = (const float*)d_in[6];
  const float* h2o_b     = (const float*)d_in[7];
  const float* h2o_ctx_w = (const float*)d_in[8];
  const float* h2o_ctx_b = (const float*)d_in[9];

  float* out      = (float*)d_out;
  float* out0     = out;
  float* out1     = out + OUT1_OFF;
  float* rate_all = out + OUT2_OFF;
  // Tagged 2-slot exchange ring: first 512KB of out0 during the recurrence;
  // overwritten with real outputs by the readout kernel afterwards.
  unsigned long long* ring = (unsigned long long*)d_out;

  // Zero the ring so stale tags (prev call/poison) never equal a live tag.
  hipMemsetAsync(ring, 0, (size_t)2 * B * H * sizeof(unsigned long long), stream);
  hipLaunchKernelGGL(rnn_recur, dim3(NGROUPS * NMEMB), dim3(512), 0, stream,
                     input_sig, rate0, i2h_w, i2h_b, h2h_w, h2h_b, rate_all, ring);
  hipLaunchKernelGGL(rnn_readout, dim3(256), dim3(256), 0, stream,
                     rate_all, h2o_w, h2o_b, h2o_ctx_w, h2o_ctx_b, out0, out1);
}

// Round 8
// 3400.911 us; speedup vs baseline: 1.4993x; 1.4651x over previous
//
#include <hip/hip_runtime.h>

constexpr int T  = 1024;
constexpr int B  = 32;
constexpr int I  = 64;
constexpr int H  = 1024;
constexpr int OF = 64;
constexpr int OC = 8;
constexpr int NG = 8;    // groups (4 batches each)
constexpr int NM = 32;   // member WGs per group (32 rows each)
constexpr long long OUT1_OFF = (long long)T * B * OF;
constexpr long long OUT2_OFF = (long long)T * B * (OF + OC);
constexpr int EXCH_F32_PER_G = 2 /*pair*/ * 2 /*slot*/ * 2048; // [k*2+b]
constexpr int EXCH_TOTAL_F32 = NG * EXCH_F32_PER_G;            // 65536 f32 = 256KB

// Agent-scope relaxed ops (global_{load,store} sc0 sc1): bypass L1/L2, meet at
// the L3 coherence point, NO cache-flush instructions. R2-proven medium.
// R4/R5/R7 lesson: sc0-only polling NEVER progresses (stale-line livelock) —
// every cross-WG access here is sc0sc1.
__device__ __forceinline__ void st_agent_f32(float* p, float v) {
  __hip_atomic_store(p, v, __ATOMIC_RELAXED, __HIP_MEMORY_SCOPE_AGENT);
}
__device__ __forceinline__ void st_agent_u32(unsigned* p, unsigned v) {
  __hip_atomic_store(p, v, __ATOMIC_RELAXED, __HIP_MEMORY_SCOPE_AGENT);
}
__device__ __forceinline__ unsigned ld_agent_u32(const unsigned* p) {
  return __hip_atomic_load(p, __ATOMIC_RELAXED, __HIP_MEMORY_SCOPE_AGENT);
}
__device__ __forceinline__ unsigned long long
ld_agent_u64(const unsigned long long* p) {
  return __hip_atomic_load(p, __ATOMIC_RELAXED, __HIP_MEMORY_SCOPE_AGENT);
}

// ---------------------------------------------------------------------------
// Recurrence: 256 persistent WGs x 512 threads (1/CU).
// Group g = bid&7 owns batches [4g,4g+4) as two independent pairs P0,P1.
// Member m = bid>>3 owns rows [m*32, m*32+32) for all 4 batches.
// Thread (rg=tid>>5, l32=tid&31): rows j=m*32+rg*2, j+1; k-slice {q*32+l32}.
// Weights register-stationary (68 fp32, shared across batches).
// State in LDS [pair][slot][k*2+b] — ds_read_b64 serves both batches, 2-way
// bank alias (free). Per step, per pair: compute -> producers store exch
// packets (agent) -> __syncthreads (vmcnt drain) -> tid0 stores flag=t+1.
// Flag one-way latency hides under the other pair's compute; restage loads
// overlap the other pair's flag poll and the next compute (software pipeline).
// Liveness: flags monotone, stored unconditionally each step after local-only
// work; polls are the only waits => deadlock-free by induction. Flags zeroed
// every call => replay-safe.
// ---------------------------------------------------------------------------
__global__ __launch_bounds__(512) void rnn_recur(
    const float* __restrict__ input_sig, const float* __restrict__ rate0,
    const float* __restrict__ i2h_w, const float* __restrict__ i2h_b,
    const float* __restrict__ h2h_w, const float* __restrict__ h2h_b,
    float* __restrict__ rate_all, float* __restrict__ exch,
    unsigned* __restrict__ flags)
{
  const int tid = threadIdx.x;
  const int bid = blockIdx.x;
  const int g   = bid & (NG - 1);
  const int m   = bid >> 3;
  const int rg  = tid >> 5;
  const int l32 = tid & 31;
  const int j   = m * 32 + rg * 2;   // this thread's rows: j, j+1
  const int bG  = g * 4;

  __shared__ float r_lds[2][2][2176];  // [pair][slot][k*2+b], k<1088

  // ---- register-stationary weights: rows j, j+1 at k = q*32+l32
  float wA[34], wB[34];
#pragma unroll
  for (int q = 0; q < 34; ++q) {
    const int k = q * 32 + l32;
    wA[q] = (k < H) ? h2h_w[(long long)j * H + k]
                    : i2h_w[(long long)j * I + (k - H)];
    wB[q] = (k < H) ? h2h_w[(long long)(j + 1) * H + k]
                    : i2h_w[(long long)(j + 1) * I + (k - H)];
  }
  const float bs0 = h2h_b[j] + i2h_b[j];
  const float bs1 = h2h_b[j + 1] + i2h_b[j + 1];

  // ---- init slot 0: r_{-1} = rate0, x_0
  if (tid < 256) {
#pragma unroll
    for (int b4 = 0; b4 < 4; ++b4) {
      float4 v = *(const float4*)(rate0 + (long long)(bG + b4) * H + tid * 4);
      float* L = &r_lds[b4 >> 1][0][0];
      const int b = b4 & 1;
      L[(tid * 4 + 0) * 2 + b] = v.x; L[(tid * 4 + 1) * 2 + b] = v.y;
      L[(tid * 4 + 2) * 2 + b] = v.z; L[(tid * 4 + 3) * 2 + b] = v.w;
    }
  }
  if (tid < 64) {
    const int bi = tid >> 4, i0 = (tid & 15) * 4;
    float4 u = *(const float4*)(input_sig + (long long)(bG + bi) * I + i0);
    float* L = &r_lds[bi >> 1][0][0];
    const int b = bi & 1;
    L[(1024 + i0 + 0) * 2 + b] = u.x; L[(1024 + i0 + 1) * 2 + b] = u.y;
    L[(1024 + i0 + 2) * 2 + b] = u.z; L[(1024 + i0 + 3) * 2 + b] = u.w;
  }
  __syncthreads();

  float* exG = exch + g * EXCH_F32_PER_G;
  unsigned long long vP0a = 0, vP0b = 0, vP1a = 0, vP1b = 0;

  for (int t = 0; t < T; ++t) {
    const int cur = t & 1, nxt = cur ^ 1;

    // K: commit P1 restage from previous iteration (loads landed during J+A)
    if (t > 0) {
      float* L1 = &r_lds[1][cur][0];
      *(float2*)&L1[2 * tid] = make_float2(
          __uint_as_float((unsigned)vP1a), __uint_as_float((unsigned)(vP1a >> 32)));
      *(float2*)&L1[2 * (tid + 512)] = make_float2(
          __uint_as_float((unsigned)vP1b), __uint_as_float((unsigned)(vP1b >> 32)));
    }
    // A2: stage x_{t+1} for all 4 batches into nxt slots
    if (tid < 64 && t + 1 < T) {
      const int bi = tid >> 4, i0 = (tid & 15) * 4;
      float4 u = *(const float4*)(input_sig +
          ((long long)(t + 1) * B + bG + bi) * I + i0);
      float* L = &r_lds[bi >> 1][nxt][0];
      const int b = bi & 1;
      L[(1024 + i0 + 0) * 2 + b] = u.x; L[(1024 + i0 + 1) * 2 + b] = u.y;
      L[(1024 + i0 + 2) * 2 + b] = u.z; L[(1024 + i0 + 3) * 2 + b] = u.w;
    }

    // ---- A: compute pair 0, producers store packets
#pragma unroll
    for (int p = 0; p < 2; ++p) {
      const float* Rb = &r_lds[p][cur][0];
      float s00 = 0.f, s01 = 0.f, s10 = 0.f, s11 = 0.f;
#pragma unroll
      for (int q = 0; q < 34; ++q) {
        const float2 v = *(const float2*)&Rb[q * 64 + 2 * l32];
        s00 = fmaf(wA[q], v.x, s00);
        s01 = fmaf(wA[q], v.y, s01);
        s10 = fmaf(wB[q], v.x, s10);
        s11 = fmaf(wB[q], v.y, s11);
      }
      // fold rows into lane halves (lower 16: row j, upper 16: row j+1)
      const float t00 = __shfl_xor(s00, 16), t10 = __shfl_xor(s10, 16);
      const float t01 = __shfl_xor(s01, 16), t11 = __shfl_xor(s11, 16);
      float u0 = (l32 < 16) ? (s00 + t00) : (s10 + t10);  // batch 0
      float u1 = (l32 < 16) ? (s01 + t01) : (s11 + t11);  // batch 1
#pragma unroll
      for (int off = 8; off >= 1; off >>= 1) {
        u0 += __shfl_xor(u0, off);
        u1 += __shfl_xor(u1, off);
      }
      // producers: lanes {0,1,16,17} of each 32-lane group
      if ((l32 & 15) < 2) {
        const int rr  = l32 >> 4;          // 0 -> row j, 1 -> row j+1
        const int b   = l32 & 1;           // batch within pair
        const int row = j + rr;
        const float val  = (b == 0) ? u0 : u1;
        const float pre  = val + (rr ? bs1 : bs0);
        const float rold = Rb[row * 2 + b];
        const float rnew = 0.9f * rold + 0.1f * tanhf(pre);
        st_agent_f32(&exG[(p * 2 + nxt) * 2048 + row * 2 + b], rnew);
        rate_all[((long long)t * B + bG + p * 2 + b) * H + row] = rnew;  // plain
      }
      __syncthreads();   // B2/D2: drain pkt stores (vmcnt0) + LDS writes
      if (tid == 0) st_agent_u32(&flags[(p * NG + g) * NM + m], (unsigned)(t + 1));
    }

    if (t + 1 < T) {
      // E: thin poll P0 flags (had a full P1-compute head start)
      if (tid < NM) {
        const unsigned* f = &flags[(0 * NG + g) * NM + tid];
        unsigned v;
        do { v = ld_agent_u32(f); } while (v < (unsigned)(t + 1));
      }
      __syncthreads();   // E2 (nothing in flight: ~free)
      // F: issue P0 restage loads (in flight during P1 poll)
      {
        const unsigned long long* e0 =
            (const unsigned long long*)&exG[(0 * 2 + nxt) * 2048];
        vP0a = ld_agent_u64(e0 + tid);
        vP0b = ld_agent_u64(e0 + tid + 512);
      }
      // G: thin poll P1 flags
      if (tid < NM) {
        const unsigned* f = &flags[(1 * NG + g) * NM + tid];
        unsigned v;
        do { v = ld_agent_u32(f); } while (v < (unsigned)(t + 1));
      }
      // G2: raw barrier (memory clobber, NO vmcnt drain -> vP0 stays in flight)
      asm volatile("s_barrier" ::: "memory");
      // H: issue P1 restage loads (consumed at K of next iteration)
      {
        const unsigned long long* e1 =
            (const unsigned long long*)&exG[(1 * 2 + nxt) * 2048];
        vP1a = ld_agent_u64(e1 + tid);
        vP1b = ld_agent_u64(e1 + tid + 512);
      }
      // I: commit P0 restage to LDS (compiler waits vP0's vmcnt here)
      {
        float* L0 = &r_lds[0][nxt][0];
        *(float2*)&L0[2 * tid] = make_float2(
            __uint_as_float((unsigned)vP0a), __uint_as_float((unsigned)(vP0a >> 32)));
        *(float2*)&L0[2 * (tid + 512)] = make_float2(
            __uint_as_float((unsigned)vP0b), __uint_as_float((unsigned)(vP0b >> 32)));
      }
      // J: LDS-drain barrier that does NOT drain vmcnt (vP1 keeps flying)
      asm volatile("s_waitcnt lgkmcnt(0)\n\ts_barrier" ::: "memory");
      __builtin_amdgcn_sched_barrier(0);
    }
  }
}

// ---------------------------------------------------------------------------
// Readout: C[32768,72] = rate_all[32768,1024] x [h2o_w;h2o_ctx_w]^T + bias
// ---------------------------------------------------------------------------
__global__ __launch_bounds__(256) void rnn_readout(
    const float* __restrict__ rate_all,
    const float* __restrict__ h2o_w, const float* __restrict__ h2o_b,
    const float* __restrict__ h2o_ctx_w, const float* __restrict__ h2o_ctx_b,
    float* __restrict__ out0, float* __restrict__ out1)
{
  constexpr int RB = 128;
  constexpr int HC = 128;
  constexpr int SR = HC + 1;
  __shared__ float rl[RB * SR];
  __shared__ float wl[72 * SR];

  const int tid = threadIdx.x;
  const long long row0 = (long long)blockIdx.x * RB;
  const int rb = tid & 31, og = tid >> 5;

  float acc[4][9];
#pragma unroll
  for (int c = 0; c < 4; ++c)
#pragma unroll
    for (int i = 0; i < 9; ++i) acc[c][i] = 0.f;

  for (int hc = 0; hc < H / HC; ++hc) {
#pragma unroll
    for (int i = 0; i < 16; ++i) {
      const int q = i * 256 + tid;
      const int row = q >> 5, hq = q & 31;
      float4 v = *(const float4*)(rate_all + (row0 + row) * H + hc * HC + hq * 4);
      float* d = &rl[row * SR + hq * 4];
      d[0] = v.x; d[1] = v.y; d[2] = v.z; d[3] = v.w;
    }
#pragma unroll
    for (int i = 0; i < 9; ++i) {
      const int q = i * 256 + tid;
      const int o = q >> 5, hq = q & 31;
      const float* src = (o < OF) ? (h2o_w + (long long)o * H)
                                  : (h2o_ctx_w + (long long)(o - OF) * H);
      float4 v = *(const float4*)(src + hc * HC + hq * 4);
      float* d = &wl[o * SR + hq * 4];
      d[0] = v.x; d[1] = v.y; d[2] = v.z; d[3] = v.w;
    }
    __syncthreads();

#pragma unroll 4
    for (int h = 0; h < HC; ++h) {
      const float r0 = rl[(rb)      * SR + h];
      const float r1 = rl[(rb + 32) * SR + h];
      const float r2 = rl[(rb + 64) * SR + h];
      const float r3 = rl[(rb + 96) * SR + h];
#pragma unroll
      for (int i = 0; i < 9; ++i) {
        const float wv = wl[(og * 9 + i) * SR + h];
        acc[0][i] = fmaf(r0, wv, acc[0][i]);
        acc[1][i] = fmaf(r1, wv, acc[1][i]);
        acc[2][i] = fmaf(r2, wv, acc[2][i]);
        acc[3][i] = fmaf(r3, wv, acc[3][i]);
      }
    }
    __syncthreads();
  }

#pragma unroll
  for (int c = 0; c < 4; ++c) {
    const long long row = row0 + rb + 32 * c;
#pragma unroll
    for (int i = 0; i < 9; ++i) {
      const int o = og * 9 + i;
      if (o < OF) out0[row * OF + o] = acc[c][i] + h2o_b[o];
      else        out1[row * OC + (o - OF)] = acc[c][i] + h2o_ctx_b[o - OF];
    }
  }
}

extern "C" void kernel_launch(void* const* d_in, const int* in_sizes, int n_in,
                              void* d_out, int out_size, void* d_ws, size_t ws_size,
                              hipStream_t stream) {
  (void)in_sizes; (void)n_in; (void)d_ws; (void)ws_size; (void)out_size;
  const float* input_sig = (const float*)d_in[0];
  const float* rate0     = (const float*)d_in[1];
  const float* i2h_w     = (const float*)d_in[2];
  const float* i2h_b     = (const float*)d_in[3];
  const float* h2h_w     = (const float*)d_in[4];
  const float* h2h_b     = (const float*)d_in[5];
  const float* h2o_w     = (const float*)d_in[6];
  const float* h2o_b     = (const float*)d_in[7];
  const float* h2o_ctx_w = (const float*)d_in[8];
  const float* h2o_ctx_b = (const float*)d_in[9];

  float* out      = (float*)d_out;
  float* out0     = out;
  float* out1     = out + OUT1_OFF;
  float* rate_all = out + OUT2_OFF;

  // Scratch in the head of out0 (overwritten by rnn_readout afterwards):
  //   [0, 256KB)        exch: [g][pair][slot][k*2+b] f32
  //   [256KB, 256KB+2KB) flags: [pair][g][m] u32 (monotone step counters)
  float*    exch  = out0;
  unsigned* flags = (unsigned*)(out0 + EXCH_TOTAL_F32);

  // Zero exch+flags EVERY call (graph-replayed): stale flags from a previous
  // call would short-circuit the polls; zero can never alias tag t+1 >= 1.
  hipMemsetAsync(d_out, 0, (size_t)(EXCH_TOTAL_F32 + 2 * NG * NM) * 4, stream);
  hipLaunchKernelGGL(rnn_recur, dim3(NG * NM), dim3(512), 0, stream,
                     input_sig, rate0, i2h_w, i2h_b, h2h_w, h2h_b,
                     rate_all, exch, flags);
  hipLaunchKernelGGL(rnn_readout, dim3(256), dim3(256), 0, stream,
                     rate_all, h2o_w, h2o_b, h2o_ctx_w, h2o_ctx_b, out0, out1);
}